// Round 4
// baseline (172.230 us; speedup 1.0000x reference)
//
#include <hip/hip_runtime.h>
#include <math.h>

// Problem constants (from reference setup_inputs)
#define BATCH 64
#define V0 32768          // 32^3
#define V1 4096           // 16^3
#define V2 512            // 8^3
#define NTOT 37376
#define K 20              // NMS_TOPK
#define M_OUT 180         // 3 * TOPK
#define NT 256            // threads per block

// Filter pipeline params
#define SLICES 32         // blocks per image in scan pass
#define SLICE4 292        // float4 per slice (292*4*32 = 37376)
#define CAP 16            // max survivors per slice buffer
#define NKEY 128          // candidate capacity (mean ~50, huge margin)
#define TLOG 3.0f         // logit filter; 20th-largest logit ~ 3.27 (z-quantile)

// Sort key: (fp32 sigmoid score bits << 32) | ~g.
// Descending u64 order == (score desc, global index asc) — matches the
// reference's lax.top_k + stable argsort tie semantics exactly.
__device__ __forceinline__ unsigned long long make_key_lo(float logit, unsigned int lo /* = ~g */) {
    float s = 1.0f / (1.0f + expf(-logit));
    return ((unsigned long long)__float_as_uint(s) << 32) | (unsigned long long)lo;
}

// Unrolled register-resident sorted-descending top-K insert (u64 keys).
#define INSERT(LV, GG) do {                                             \
    unsigned long long ck_ = make_key_lo((LV), ~(GG));                  \
    if (ck_ > keys[K-1]) {                                              \
        _Pragma("unroll")                                               \
        for (int j_ = 0; j_ < K; ++j_) {                                \
            if (ck_ > keys[j_]) {                                       \
                unsigned long long t_ = keys[j_]; keys[j_] = ck_; ck_ = t_; \
            }                                                           \
        }                                                               \
    }                                                                   \
} while (0)

// ---- Exact full-image top-20 (fallback path; never taken on this input) ----
// Per-thread INSERT scan + 20-round block max-reduce over list heads (2KB LDS).
__device__ void fullscan_select(
    int b, int tid,
    const float* __restrict__ cls0, const float* __restrict__ cls1, const float* __restrict__ cls2,
    unsigned long long* heads /* LDS[NT] */, unsigned long long* sorted /* LDS[K] */)
{
    unsigned long long keys[K];
#pragma unroll
    for (int j = 0; j < K; ++j) keys[j] = 0ull;
    {
        const float4* c0 = (const float4*)(cls0 + (size_t)b * V0);
#pragma unroll 1
        for (int it = 0; it < V0 / (4 * NT); ++it) {
            int i4 = tid + it * NT;
            float4 v = c0[i4];
            unsigned int g = 4u * (unsigned int)i4;
            INSERT(v.x, g); INSERT(v.y, g + 1); INSERT(v.z, g + 2); INSERT(v.w, g + 3);
        }
        const float4* c1 = (const float4*)(cls1 + (size_t)b * V1);
#pragma unroll 1
        for (int it = 0; it < V1 / (4 * NT); ++it) {
            int i4 = tid + it * NT;
            float4 v = c1[i4];
            unsigned int g = V0 + 4u * (unsigned int)i4;
            INSERT(v.x, g); INSERT(v.y, g + 1); INSERT(v.z, g + 2); INSERT(v.w, g + 3);
        }
        if (tid < V2 / 4) {
            const float4* c2 = (const float4*)(cls2 + (size_t)b * V2);
            float4 v = c2[tid];
            unsigned int g = V0 + V1 + 4u * (unsigned int)tid;
            INSERT(v.x, g); INSERT(v.y, g + 1); INSERT(v.z, g + 2); INSERT(v.w, g + 3);
        }
    }
    int h = 0;
    for (int r = 0; r < K; ++r) {
        heads[tid] = (h < K) ? keys[h] : 0ull;
        __syncthreads();
        for (int off = NT / 2; off >= 1; off >>= 1) {
            if (tid < off) {
                unsigned long long o = heads[tid + off];
                if (o > heads[tid]) heads[tid] = o;
            }
            __syncthreads();
        }
        unsigned long long win = heads[0];
        __syncthreads();                       // all read win before heads reused
        if (tid == 0) sorted[r] = win;
        unsigned long long mine = (h < K) ? keys[h] : 0ull;
        if (mine == win && win != 0ull) ++h;   // keys distinct => unique owner
    }
    __syncthreads();
}

// ---- Decode + IoU + greedy NMS + output write (per image) ----
__device__ void tail_process(
    int b, int tid,
    const float* __restrict__ shp0, const float* __restrict__ off0,
    const float* __restrict__ shp1, const float* __restrict__ off1,
    const float* __restrict__ shp2, const float* __restrict__ off2,
    const unsigned long long* sorted /* LDS[K] */,
    float (*sBox)[6], float* sScore, int* sValid, float* sIou, int* sRow,
    float* __restrict__ out)
{
    if (tid < K) {
        unsigned long long key = sorted[tid];
        float score = __uint_as_float((unsigned int)(key >> 32));
        unsigned int g = ~((unsigned int)key);
        sScore[tid] = score;
        sValid[tid] = (score > 0.15f) ? 1 : 0;

        int v, D;
        const float* sp; const float* op;
        if (g < V0)           { v = (int)g;             D = 32; sp = shp0; op = off0; }
        else if (g < V0 + V1) { v = (int)(g - V0);      D = 16; sp = shp1; op = off1; }
        else                  { v = (int)(g - V0 - V1); D = 8;  sp = shp2; op = off2; }
        int Vl = D * D * D, HW = D * D;
        int z = v / HW, rem = v - z * HW, y = rem / D, x = rem - y * D;
        float stride = 128.0f / (float)D;
        const float* opb = op + (size_t)b * 3 * Vl;
        const float* spb = sp + (size_t)b * 3 * Vl;
        sBox[tid][0] = ((float)z + opb[v])          * stride;
        sBox[tid][1] = ((float)y + opb[Vl + v])     * stride;
        sBox[tid][2] = ((float)x + opb[2 * Vl + v]) * stride;
        sBox[tid][3] = spb[v];
        sBox[tid][4] = spb[Vl + v];
        sBox[tid][5] = spb[2 * Vl + v];
    }
    __syncthreads();

    // Pairwise 3D IoU (20x20). fp contract off: np computes c±0.5*s mul-then-add.
    for (int p = tid; p < K * K; p += NT) {
#pragma clang fp contract(off)
        int i = p / K, j = p % K;
        float ci0 = sBox[i][0], ci1 = sBox[i][1], ci2 = sBox[i][2];
        float si0 = fmaxf(sBox[i][3], 0.0f), si1 = fmaxf(sBox[i][4], 0.0f), si2 = fmaxf(sBox[i][5], 0.0f);
        float cj0 = sBox[j][0], cj1 = sBox[j][1], cj2 = sBox[j][2];
        float sj0 = fmaxf(sBox[j][3], 0.0f), sj1 = fmaxf(sBox[j][4], 0.0f), sj2 = fmaxf(sBox[j][5], 0.0f);
        float in0 = fmaxf(fminf(ci0 + 0.5f * si0, cj0 + 0.5f * sj0) - fmaxf(ci0 - 0.5f * si0, cj0 - 0.5f * sj0), 0.0f);
        float in1 = fmaxf(fminf(ci1 + 0.5f * si1, cj1 + 0.5f * sj1) - fmaxf(ci1 - 0.5f * si1, cj1 - 0.5f * sj1), 0.0f);
        float in2 = fmaxf(fminf(ci2 + 0.5f * si2, cj2 + 0.5f * sj2) - fmaxf(ci2 - 0.5f * si2, cj2 - 0.5f * sj2), 0.0f);
        float inter = in0 * in1 * in2;
        float voli = si0 * si1 * si2, volj = sj0 * sj1 * sj2;
        sIou[p] = inter / (voli + volj - inter + 1e-8f);
    }
    __syncthreads();

    if (tid == 0) {
        int keep[K];
        int cnt = 0;
#pragma unroll
        for (int i = 0; i < K; ++i) sRow[i] = -1;
        for (int i = 0; i < K; ++i) {
            int sup = 0;
            for (int j = 0; j < i; ++j)
                sup |= (keep[j] && (sIou[i * K + j] > 0.05f));
            keep[i] = sValid[i] && !sup;
            if (keep[i]) { sRow[cnt] = i; ++cnt; }
        }
    }
    __syncthreads();

    float* ob = out + (size_t)b * (M_OUT * 8);
    for (int e = tid; e < M_OUT * 8; e += NT) {
        int r = e >> 3, c = e & 7;
        float val = -1.0f;
        if (r < K) {
            int i = sRow[r];
            if (i >= 0) {
                if (c == 0)      val = 1.0f;
                else if (c == 1) val = sScore[i];
                else             val = sBox[i][c - 2];
            }
        }
        ob[e] = val;
    }
}

// ---------------- Fused: scan + last-block-per-image finalize ----------------
__global__ __launch_bounds__(NT) void fused_kernel(
    const float* __restrict__ cls0, const float* __restrict__ shp0, const float* __restrict__ off0,
    const float* __restrict__ cls1, const float* __restrict__ shp1, const float* __restrict__ off1,
    const float* __restrict__ cls2, const float* __restrict__ shp2, const float* __restrict__ off2,
    unsigned long long* __restrict__ wsKeys, int* __restrict__ wsCnt, int* __restrict__ done,
    float* __restrict__ out)
{
    const int blk = blockIdx.x;          // 0..BATCH*SLICES-1
    const int b = blk >> 5, s = blk & 31;
    const int tid = threadIdx.x;

    __shared__ int lcnt;
    __shared__ int sLast;
    __shared__ unsigned long long heads[NT];   // 2 KB (fallback reduce)
    __shared__ unsigned long long lkeys[NKEY]; // 1 KB
    __shared__ unsigned long long sorted[K];
    __shared__ int cnts[SLICES];
    __shared__ int pfx[SLICES];
    __shared__ int sDegen;
    __shared__ float sBox[K][6];
    __shared__ float sScore[K];
    __shared__ int   sValid[K];
    __shared__ float sIou[K * K];
    __shared__ int   sRow[K];

    if (tid == 0) lcnt = 0;
    __syncthreads();

    // ---- scan this slice ----
    const int base4 = s * SLICE4;
    for (int i4 = tid; i4 < SLICE4; i4 += NT) {
        int f4 = base4 + i4;
        float4 v;
        if (f4 < V0 / 4)             v = ((const float4*)(cls0 + (size_t)b * V0))[f4];
        else if (f4 < (V0 + V1) / 4) v = ((const float4*)(cls1 + (size_t)b * V1))[f4 - V0 / 4];
        else                         v = ((const float4*)(cls2 + (size_t)b * V2))[f4 - (V0 + V1) / 4];
        unsigned int g = 4u * (unsigned int)f4;
        float aa[4] = {v.x, v.y, v.z, v.w};
#pragma unroll
        for (int c = 0; c < 4; ++c) {
            if (aa[c] > TLOG) {
                int slot = atomicAdd(&lcnt, 1);
                if (slot < CAP)
                    wsKeys[(size_t)blk * CAP + slot] =
                        ((unsigned long long)__float_as_uint(aa[c]) << 32) |
                        (unsigned long long)(~(g + (unsigned int)c));
            }
        }
    }
    __syncthreads();

    // ---- publish + last-block election (device-scope acq_rel) ----
    if (tid == 0) {
        wsCnt[blk] = lcnt;
        int old = __hip_atomic_fetch_add(&done[b], 1, __ATOMIC_ACQ_REL,
                                         __HIP_MEMORY_SCOPE_AGENT);
        sLast = (old == SLICES - 1) ? 1 : 0;
    }
    __syncthreads();
    if (!sLast) return;

    // ---- finalize image b (this block only) ----
    if (tid < SLICES) cnts[tid] = wsCnt[b * SLICES + tid];
    __syncthreads();
    if (tid == 0) {
        int dg = 0, t = 0;
        for (int q = 0; q < SLICES; ++q) {
            pfx[q] = t;
            int c = cnts[q];
            if (c > CAP) dg = 1;
            t += c;
        }
        if (t < K || t > NKEY) dg = 1;
        sDegen = dg;
    }
    __syncthreads();

    if (!sDegen) {
        // fast path: gather survivors, exact rank-select top-20
        for (int t = tid; t < NKEY; t += NT) lkeys[t] = 0ull;
        __syncthreads();
        for (int t = tid; t < SLICES * CAP; t += NT) {
            int q = t / CAP, i = t % CAP;
            if (i < cnts[q]) {
                unsigned long long pk = wsKeys[(size_t)(b * SLICES + q) * CAP + i];
                float logit = __uint_as_float((unsigned int)(pk >> 32));
                lkeys[pfx[q] + i] = make_key_lo(logit, (unsigned int)pk);
            }
        }
        __syncthreads();
        if (tid < NKEY) {
            unsigned long long my = lkeys[tid];
            int rank = 0;
#pragma unroll 8
            for (int i = 0; i < NKEY; ++i) rank += (lkeys[i] > my) ? 1 : 0;
            if (my != 0ull && rank < K) sorted[rank] = my;   // distinct keys => unique ranks
        }
        __syncthreads();
    } else {
        fullscan_select(b, tid, cls0, cls1, cls2, heads, sorted);
    }

    tail_process(b, tid, shp0, off0, shp1, off1, shp2, off2,
                 sorted, sBox, sScore, sValid, sIou, sRow, out);
}

// ---------------- Standalone exact kernel (only if ws too small) ----------------
__global__ __launch_bounds__(NT) void exact_kernel(
    const float* __restrict__ cls0, const float* __restrict__ shp0, const float* __restrict__ off0,
    const float* __restrict__ cls1, const float* __restrict__ shp1, const float* __restrict__ off1,
    const float* __restrict__ cls2, const float* __restrict__ shp2, const float* __restrict__ off2,
    float* __restrict__ out)
{
    const int b = blockIdx.x;
    const int tid = threadIdx.x;
    __shared__ unsigned long long heads[NT];
    __shared__ unsigned long long sorted[K];
    __shared__ float sBox[K][6];
    __shared__ float sScore[K];
    __shared__ int   sValid[K];
    __shared__ float sIou[K * K];
    __shared__ int   sRow[K];

    fullscan_select(b, tid, cls0, cls1, cls2, heads, sorted);
    tail_process(b, tid, shp0, off0, shp1, off1, shp2, off2,
                 sorted, sBox, sScore, sValid, sIou, sRow, out);
}

extern "C" void kernel_launch(void* const* d_in, const int* in_sizes, int n_in,
                              void* d_out, int out_size, void* d_ws, size_t ws_size,
                              hipStream_t stream) {
    const float* cls0 = (const float*)d_in[0];
    const float* shp0 = (const float*)d_in[1];
    const float* off0 = (const float*)d_in[2];
    const float* cls1 = (const float*)d_in[3];
    const float* shp1 = (const float*)d_in[4];
    const float* off1 = (const float*)d_in[5];
    const float* cls2 = (const float*)d_in[6];
    const float* shp2 = (const float*)d_in[7];
    const float* off2 = (const float*)d_in[8];
    float* out = (float*)d_out;

    const size_t keysBytes = (size_t)BATCH * SLICES * CAP * sizeof(unsigned long long); // 256 KB
    const size_t cntBytes  = (size_t)BATCH * SLICES * sizeof(int);                      // 8 KB
    const size_t doneBytes = (size_t)BATCH * sizeof(int);                               // 256 B
    const size_t needBytes = keysBytes + cntBytes + doneBytes;

    if (ws_size >= needBytes) {
        unsigned long long* wsKeys = (unsigned long long*)d_ws;
        int* wsCnt = (int*)((char*)d_ws + keysBytes);
        int* done  = (int*)((char*)d_ws + keysBytes + cntBytes);
        hipMemsetAsync(done, 0, doneBytes, stream);
        fused_kernel<<<BATCH * SLICES, NT, 0, stream>>>(
            cls0, shp0, off0, cls1, shp1, off1, cls2, shp2, off2,
            wsKeys, wsCnt, done, out);
    } else {
        exact_kernel<<<BATCH, NT, 0, stream>>>(
            cls0, shp0, off0, cls1, shp1, off1, cls2, shp2, off2, out);
    }
}

// Round 5
// 113.124 us; speedup vs baseline: 1.5225x; 1.5225x over previous
//
#include <hip/hip_runtime.h>
#include <math.h>

// Problem constants (from reference setup_inputs)
#define BATCH 64
#define V0 32768          // 32^3
#define V1 4096           // 16^3
#define V2 512            // 8^3
#define NTOT 37376
#define K 20              // NMS_TOPK
#define M_OUT 180         // 3 * TOPK
#define NT 256            // threads per block

// Filter pipeline params
#define SLICES 32         // blocks per image in scan pass
#define SLICE4 292        // float4 per slice (292*4*32 = 37376)
#define CAP 16            // max survivors per slice buffer
#define NKEY 128          // pass-B candidate capacity (mean ~50, 11 sigma margin)
#define TLOG 3.0f         // logit filter; 20th-largest logit ~ 3.27 (z-quantile)

// NOTE (R4 post-mortem): do NOT fuse these two kernels with per-block
// agent-scope acq_rel atomics — on gfx950 each release implies a full L2
// writeback (per-XCD L2s are non-coherent), and 2048 of them serialized the
// kernel to ~85 µs (VALUBusy ~1%). The kernel boundary below provides the
// same ordering with one implicit flush.

// Sort key: (fp32 sigmoid score bits << 32) | ~g.
// Descending u64 order == (score desc, global index asc) — matches the
// reference's lax.top_k + stable argsort tie semantics exactly.
__device__ __forceinline__ unsigned long long make_key_lo(float logit, unsigned int lo /* = ~g */) {
    float s = 1.0f / (1.0f + expf(-logit));
    return ((unsigned long long)__float_as_uint(s) << 32) | (unsigned long long)lo;
}

// Unrolled register-resident sorted-descending top-K insert (u64 keys).
#define INSERT(LV, GG) do {                                             \
    unsigned long long ck_ = make_key_lo((LV), ~(GG));                  \
    if (ck_ > keys[K-1]) {                                              \
        _Pragma("unroll")                                               \
        for (int j_ = 0; j_ < K; ++j_) {                                \
            if (ck_ > keys[j_]) {                                       \
                unsigned long long t_ = keys[j_]; keys[j_] = ck_; ck_ = t_; \
            }                                                           \
        }                                                               \
    }                                                                   \
} while (0)

// ---------------- Pass A: threshold scan ----------------
__global__ __launch_bounds__(NT) void scan_kernel(
    const float* __restrict__ cls0, const float* __restrict__ cls1, const float* __restrict__ cls2,
    unsigned long long* __restrict__ wsKeys, int* __restrict__ wsCnt)
{
    const int blk = blockIdx.x;
    const int b = blk >> 5, s = blk & 31;
    const int tid = threadIdx.x;
    __shared__ int lcnt;
    if (tid == 0) lcnt = 0;
    __syncthreads();

    const int base4 = s * SLICE4;
    for (int i4 = tid; i4 < SLICE4; i4 += NT) {
        int f4 = base4 + i4;               // float4 index in image-flat logit space
        float4 v;
        if (f4 < V0 / 4)                 v = ((const float4*)(cls0 + (size_t)b * V0))[f4];
        else if (f4 < (V0 + V1) / 4)     v = ((const float4*)(cls1 + (size_t)b * V1))[f4 - V0 / 4];
        else                             v = ((const float4*)(cls2 + (size_t)b * V2))[f4 - (V0 + V1) / 4];
        unsigned int g = 4u * (unsigned int)f4;
        float aa[4] = {v.x, v.y, v.z, v.w};
#pragma unroll
        for (int c = 0; c < 4; ++c) {
            if (aa[c] > TLOG) {
                int slot = atomicAdd(&lcnt, 1);
                if (slot < CAP)
                    wsKeys[(size_t)blk * CAP + slot] =
                        ((unsigned long long)__float_as_uint(aa[c]) << 32) |
                        (unsigned long long)(~(g + (unsigned int)c));
            }
        }
    }
    __syncthreads();
    if (tid == 0) wsCnt[blk] = lcnt;
}

// ---------------- Pass B: select + decode + NMS + write ----------------
__global__ __launch_bounds__(NT) void final_kernel(
    const float* __restrict__ cls0, const float* __restrict__ shp0, const float* __restrict__ off0,
    const float* __restrict__ cls1, const float* __restrict__ shp1, const float* __restrict__ off1,
    const float* __restrict__ cls2, const float* __restrict__ shp2, const float* __restrict__ off2,
    const unsigned long long* __restrict__ wsKeys, const int* __restrict__ wsCnt,
    float* __restrict__ out, int use_ws)
{
    const int b   = blockIdx.x;
    const int tid = threadIdx.x;

    __shared__ unsigned long long sKeys[NT * K];   // 40 KB (fallback merge space)
    __shared__ unsigned long long lkeys[NKEY];
    __shared__ unsigned long long sorted[K];
    __shared__ int cnts[SLICES];
    __shared__ int pfx[SLICES];
    __shared__ int sDegen;
    __shared__ float sBox[K][6];
    __shared__ float sScore[K];
    __shared__ int   sValid[K];
    __shared__ float sIou[K * K];
    __shared__ int   sRow[K];

    // Load per-slice counts, compute prefix + degeneracy (fast path validity)
    if (use_ws && tid < SLICES) cnts[tid] = wsCnt[b * SLICES + tid];
    __syncthreads();
    if (tid == 0) {
        int dg = !use_ws, t = 0;
        if (use_ws) {
            for (int s = 0; s < SLICES; ++s) {
                pfx[s] = t;
                int c = cnts[s];
                if (c > CAP) dg = 1;
                t += c;
            }
            if (t < K || t > NKEY) dg = 1;
        }
        sDegen = dg;
    }
    __syncthreads();

    if (!sDegen) {
        // -------- fast path: gather survivors, exact rank-select top-20 --------
        for (int t = tid; t < NKEY; t += NT) lkeys[t] = 0ull;
        __syncthreads();
        for (int t = tid; t < SLICES * CAP; t += NT) {
            int s = t / CAP, i = t % CAP;
            if (i < cnts[s]) {
                unsigned long long pk = wsKeys[(size_t)(b * SLICES + s) * CAP + i];
                float logit = __uint_as_float((unsigned int)(pk >> 32));
                lkeys[pfx[s] + i] = make_key_lo(logit, (unsigned int)pk);
            }
        }
        __syncthreads();
        if (tid < NKEY) {
            unsigned long long my = lkeys[tid];
            int rank = 0;
#pragma unroll 8
            for (int i = 0; i < NKEY; ++i) rank += (lkeys[i] > my) ? 1 : 0;
            if (my != 0ull && rank < K) sorted[rank] = my;   // keys distinct => ranks unique
        }
        __syncthreads();
    } else {
        // -------- exact fallback: full-image scan (R2-proven path) --------
        unsigned long long keys[K];
#pragma unroll
        for (int j = 0; j < K; ++j) keys[j] = 0ull;
        {
            const float4* c0 = (const float4*)(cls0 + (size_t)b * V0);
#pragma unroll 1
            for (int it = 0; it < V0 / (4 * NT); ++it) {
                int i4 = tid + it * NT;
                float4 v = c0[i4];
                unsigned int g = 4u * (unsigned int)i4;
                INSERT(v.x, g); INSERT(v.y, g + 1); INSERT(v.z, g + 2); INSERT(v.w, g + 3);
            }
            const float4* c1 = (const float4*)(cls1 + (size_t)b * V1);
#pragma unroll 1
            for (int it = 0; it < V1 / (4 * NT); ++it) {
                int i4 = tid + it * NT;
                float4 v = c1[i4];
                unsigned int g = V0 + 4u * (unsigned int)i4;
                INSERT(v.x, g); INSERT(v.y, g + 1); INSERT(v.z, g + 2); INSERT(v.w, g + 3);
            }
            if (tid < V2 / 4) {
                const float4* c2 = (const float4*)(cls2 + (size_t)b * V2);
                float4 v = c2[tid];
                unsigned int g = V0 + V1 + 4u * (unsigned int)tid;
                INSERT(v.x, g); INSERT(v.y, g + 1); INSERT(v.z, g + 2); INSERT(v.w, g + 3);
            }
        }
#pragma unroll
        for (int j = 0; j < K; ++j) sKeys[tid * K + j] = keys[j];
        for (int half = NT / 2; half >= 1; half >>= 1) {
            __syncthreads();
            if (tid < half) {
                int aB = tid * K, bB = (tid + half) * K;
                unsigned long long ov[K];
                int ia = 0, ib = 0;
                unsigned long long av = sKeys[aB], bv = sKeys[bB];
#pragma unroll
                for (int p = 0; p < K; ++p) {
                    bool ta = (av >= bv);
                    ov[p] = ta ? av : bv;
                    if (ta) { ++ia; av = (ia < K) ? sKeys[aB + ia] : 0ull; }
                    else    { ++ib; bv = (ib < K) ? sKeys[bB + ib] : 0ull; }
                }
#pragma unroll
                for (int p = 0; p < K; ++p) sKeys[aB + p] = ov[p];
            }
        }
        __syncthreads();
        if (tid < K) sorted[tid] = sKeys[tid];
        __syncthreads();
    }

    // ---------------- Decode top-20 candidates ----------------
    if (tid < K) {
        unsigned long long key = sorted[tid];
        float score = __uint_as_float((unsigned int)(key >> 32));
        unsigned int g = ~((unsigned int)key);
        sScore[tid] = score;
        sValid[tid] = (score > 0.15f) ? 1 : 0;

        int v, D;
        const float* sp; const float* op;
        if (g < V0)           { v = (int)g;             D = 32; sp = shp0; op = off0; }
        else if (g < V0 + V1) { v = (int)(g - V0);      D = 16; sp = shp1; op = off1; }
        else                  { v = (int)(g - V0 - V1); D = 8;  sp = shp2; op = off2; }
        int Vl = D * D * D, HW = D * D;
        int z = v / HW, rem = v - z * HW, y = rem / D, x = rem - y * D;
        float stride = 128.0f / (float)D;
        const float* opb = op + (size_t)b * 3 * Vl;
        const float* spb = sp + (size_t)b * 3 * Vl;
        sBox[tid][0] = ((float)z + opb[v])          * stride;
        sBox[tid][1] = ((float)y + opb[Vl + v])     * stride;
        sBox[tid][2] = ((float)x + opb[2 * Vl + v]) * stride;
        sBox[tid][3] = spb[v];
        sBox[tid][4] = spb[Vl + v];
        sBox[tid][5] = spb[2 * Vl + v];
    }
    __syncthreads();

    // ---------------- Pairwise 3D IoU (20x20) ----------------
    // fp contract off: np reference computes c ± 0.5*s as mul-then-add, not FMA.
    for (int p = tid; p < K * K; p += NT) {
#pragma clang fp contract(off)
        int i = p / K, j = p % K;
        float ci0 = sBox[i][0], ci1 = sBox[i][1], ci2 = sBox[i][2];
        float si0 = fmaxf(sBox[i][3], 0.0f), si1 = fmaxf(sBox[i][4], 0.0f), si2 = fmaxf(sBox[i][5], 0.0f);
        float cj0 = sBox[j][0], cj1 = sBox[j][1], cj2 = sBox[j][2];
        float sj0 = fmaxf(sBox[j][3], 0.0f), sj1 = fmaxf(sBox[j][4], 0.0f), sj2 = fmaxf(sBox[j][5], 0.0f);
        float in0 = fmaxf(fminf(ci0 + 0.5f * si0, cj0 + 0.5f * sj0) - fmaxf(ci0 - 0.5f * si0, cj0 - 0.5f * sj0), 0.0f);
        float in1 = fmaxf(fminf(ci1 + 0.5f * si1, cj1 + 0.5f * sj1) - fmaxf(ci1 - 0.5f * si1, cj1 - 0.5f * sj1), 0.0f);
        float in2 = fmaxf(fminf(ci2 + 0.5f * si2, cj2 + 0.5f * sj2) - fmaxf(ci2 - 0.5f * si2, cj2 - 0.5f * sj2), 0.0f);
        float inter = in0 * in1 * in2;
        float voli = si0 * si1 * si2, volj = sj0 * sj1 * sj2;
        sIou[p] = inter / (voli + volj - inter + 1e-8f);
    }
    __syncthreads();

    // ---------------- Greedy NMS (sequential, thread 0) ----------------
    if (tid == 0) {
        int keep[K];
        int cnt = 0;
#pragma unroll
        for (int i = 0; i < K; ++i) sRow[i] = -1;
        for (int i = 0; i < K; ++i) {
            int sup = 0;
            for (int j = 0; j < i; ++j)
                sup |= (keep[j] && (sIou[i * K + j] > 0.05f));
            keep[i] = sValid[i] && !sup;
            if (keep[i]) { sRow[cnt] = i; ++cnt; }
        }
    }
    __syncthreads();

    // ---------------- Write output: [180][8] per image ----------------
    float* ob = out + (size_t)b * (M_OUT * 8);
    for (int e = tid; e < M_OUT * 8; e += NT) {
        int r = e >> 3, c = e & 7;
        float val = -1.0f;
        if (r < K) {
            int i = sRow[r];
            if (i >= 0) {
                if (c == 0)      val = 1.0f;
                else if (c == 1) val = sScore[i];
                else             val = sBox[i][c - 2];
            }
        }
        ob[e] = val;
    }
}

extern "C" void kernel_launch(void* const* d_in, const int* in_sizes, int n_in,
                              void* d_out, int out_size, void* d_ws, size_t ws_size,
                              hipStream_t stream) {
    const float* cls0 = (const float*)d_in[0];
    const float* shp0 = (const float*)d_in[1];
    const float* off0 = (const float*)d_in[2];
    const float* cls1 = (const float*)d_in[3];
    const float* shp1 = (const float*)d_in[4];
    const float* off1 = (const float*)d_in[5];
    const float* cls2 = (const float*)d_in[6];
    const float* shp2 = (const float*)d_in[7];
    const float* off2 = (const float*)d_in[8];
    float* out = (float*)d_out;

    const size_t keysBytes = (size_t)BATCH * SLICES * CAP * sizeof(unsigned long long); // 256 KB
    const size_t needBytes = keysBytes + (size_t)BATCH * SLICES * sizeof(int);

    if (ws_size >= needBytes) {
        unsigned long long* wsKeys = (unsigned long long*)d_ws;
        int* wsCnt = (int*)((char*)d_ws + keysBytes);
        scan_kernel<<<BATCH * SLICES, NT, 0, stream>>>(cls0, cls1, cls2, wsKeys, wsCnt);
        final_kernel<<<BATCH, NT, 0, stream>>>(cls0, shp0, off0, cls1, shp1, off1,
                                               cls2, shp2, off2, wsKeys, wsCnt, out, 1);
    } else {
        final_kernel<<<BATCH, NT, 0, stream>>>(cls0, shp0, off0, cls1, shp1, off1,
                                               cls2, shp2, off2, nullptr, nullptr, out, 0);
    }
}